// Round 15
// baseline (348.635 us; speedup 1.0000x reference)
//
#include <hip/hip_runtime.h>
#include <hip/hip_fp16.h>

#define HID 64
#define SH 9          // log2(nodes per bucket)
#define BKN 512       // nodes per bucket
#define MAXB1 256     // max buckets supported (n <= 131072)
#define NBLK 512      // edge-chunk blocks for the counting sort
#define MAXPAIR 24576 // LDS pair-cache (96 KB); expected bucket size ~16.3K
typedef unsigned int u32;

// 16 fmafs: acc (float4 over cols) += xs[k] * w_k row-vectors
#define FMA4(acc, xs, w0, w1, w2, w3)                                          \
  acc.x = fmaf(xs.w, w3.x, fmaf(xs.z, w2.x, fmaf(xs.y, w1.x, fmaf(xs.x, w0.x, acc.x)))); \
  acc.y = fmaf(xs.w, w3.y, fmaf(xs.z, w2.y, fmaf(xs.y, w1.y, fmaf(xs.x, w0.y, acc.y)))); \
  acc.z = fmaf(xs.w, w3.z, fmaf(xs.z, w2.z, fmaf(xs.y, w1.z, fmaf(xs.x, w0.z, acc.z)))); \
  acc.w = fmaf(xs.w, w3.w, fmaf(xs.z, w2.w, fmaf(xs.y, w1.w, fmaf(xs.x, w0.w, acc.w))))

// ---------------------------------------------------------------- per-(block,bucket) histogram
__global__ __launch_bounds__(256) void count_chunks(const int* __restrict__ dst,
                                                    int* __restrict__ cnt2,
                                                    int E, int nbk) {
  __shared__ int lc[MAXB1];
  const int t = threadIdx.x;
  for (int b = t; b < nbk; b += 256) lc[b] = 0;
  __syncthreads();
  const int C = (E + NBLK - 1) / NBLK;
  const int s0 = blockIdx.x * C;
  const int s1 = min(s0 + C, E);
  for (int i = s0 + t; i < s1; i += 256) atomicAdd(&lc[dst[i] >> SH], 1);
  __syncthreads();
  for (int b = t; b < nbk; b += 256)
    cnt2[(size_t)b * NBLK + blockIdx.x] = lc[b];  // bucket-major for the scan
}

// ---------------------------------------------------------------- hierarchical scan (cnt2)
__global__ __launch_bounds__(256) void scan_blocks(const int* __restrict__ v_in,
                                                   int* __restrict__ excl,
                                                   int* __restrict__ bsum, int n) {
  __shared__ int s[256];
  const int t = threadIdx.x;
  const int i = blockIdx.x * 256 + t;
  const int v = (i < n) ? v_in[i] : 0;
  s[t] = v;
  __syncthreads();
  for (int off = 1; off < 256; off <<= 1) {
    const int u = (t >= off) ? s[t - off] : 0;
    __syncthreads();
    s[t] += u;
    __syncthreads();
  }
  if (i < n) excl[i] = s[t] - v;
  if (t == 255) bsum[blockIdx.x] = s[255];
}

__global__ __launch_bounds__(512) void scan_top(int* bsum, int nb) {
  __shared__ int s[512];
  const int t = threadIdx.x;
  const int v = (t < nb) ? bsum[t] : 0;
  s[t] = v;
  __syncthreads();
  for (int off = 1; off < 512; off <<= 1) {
    const int u = (t >= off) ? s[t - off] : 0;
    __syncthreads();
    s[t] += u;
    __syncthreads();
  }
  if (t < nb) bsum[t] = s[t] - v;
}

__global__ __launch_bounds__(256) void add_offsets2(int* __restrict__ off,
                                                    const int* __restrict__ bsum,
                                                    int* __restrict__ boff,
                                                    int NE, int E, int nbk) {
  const int m = blockIdx.x * 256 + threadIdx.x;
  if (m < NE) {
    const int v = off[m] + bsum[blockIdx.x];
    off[m] = v;
    if ((m & (NBLK - 1)) == 0) boff[m >> 9] = v;  // NBLK = 512
  }
  if (m == 0) boff[nbk] = E;
}

// ---------------------------------------------------------------- fill pairs (deterministic)
// packed u32: (dstLocal<<17) | src
__global__ __launch_bounds__(256) void fill_pairs(const int* __restrict__ src,
                                                  const int* __restrict__ dst,
                                                  const int* __restrict__ off,
                                                  u32* __restrict__ pairs,
                                                  int E, int nbk) {
  __shared__ int lbase[MAXB1];
  __shared__ int lrank[MAXB1];
  const int t = threadIdx.x;
  for (int b = t; b < nbk; b += 256) {
    lbase[b] = off[(size_t)b * NBLK + blockIdx.x];
    lrank[b] = 0;
  }
  __syncthreads();
  const int C = (E + NBLK - 1) / NBLK;
  const int s0 = blockIdx.x * C;
  const int s1 = min(s0 + C, E);
  for (int i = s0 + t; i < s1; i += 256) {
    const int d = dst[i];
    const int b = d >> SH;
    const int r = atomicAdd(&lrank[b], 1);
    pairs[lbase[b] + r] = ((u32)(d & (BKN - 1)) << 17) | (u32)src[i];
  }
}

// ---------------------------------------------------------------- fused CSR build
__global__ __launch_bounds__(512) void bucket_csr(const u32* __restrict__ pairs,
                                                  const int* __restrict__ boff,
                                                  int* __restrict__ rowptr,
                                                  float* __restrict__ dinv,
                                                  int* __restrict__ colidx,
                                                  int n, int nbk) {
  __shared__ u32 pc[MAXPAIR];  // 96 KB pair cache
  __shared__ int ldeg[BKN];
  __shared__ int lofs[BKN];
  const int bkt = blockIdx.x;
  const int t = threadIdx.x;
  ldeg[t] = 0;
  __syncthreads();
  const int beg = boff[bkt], end = boff[bkt + 1];
  const int cnt = end - beg;
  const bool cached = (cnt <= MAXPAIR);
  for (int e = t; e < cnt; e += 512) {
    const u32 p = pairs[beg + e];
    if (cached) pc[e] = p;
    atomicAdd(&ldeg[p >> 17], 1);
  }
  __syncthreads();
  const int v = ldeg[t];
  lofs[t] = v;
  __syncthreads();
  for (int o = 1; o < 512; o <<= 1) {  // Hillis-Steele inclusive scan
    const int u = (t >= o) ? lofs[t - o] : 0;
    __syncthreads();
    lofs[t] += u;
    __syncthreads();
  }
  const int base = beg + lofs[t] - v;  // exclusive
  const int node = bkt * BKN + t;
  if (node < n) {
    rowptr[node] = base;
    dinv[node] = rsqrtf((float)(v + 1));  // +1 self-loop
  }
  if (bkt == nbk - 1 && t == 511) rowptr[n] = end;  // == E
  __syncthreads();
  ldeg[t] = base;  // reuse as absolute cursor
  __syncthreads();
  for (int e = t; e < cnt; e += 512) {
    const u32 p = cached ? pc[e] : pairs[beg + e];
    const int pos = atomicAdd(&ldeg[p >> 17], 1);
    colidx[pos] = (int)(p & 0x1FFFF);
  }
}

// ---------------------------------------------------------------- dense transform (fp32 in, K=128)
// 64-row blocks, 4x4 register tile per thread: 2 B LDS traffic per fmaf.
__global__ __launch_bounds__(256) void gemm_rt128(const float* __restrict__ x,
                                                  const float* __restrict__ W,
                                                  const float* __restrict__ dinv,
                                                  __half* __restrict__ out, int n) {
  __shared__ float Wl[128 * 64];   // 32 KB
  __shared__ float xl[64][132];    // 33.8 KB (pad 4 -> 2-way-free banks)
  const int tid = threadIdx.x;
  for (int i = tid; i < 128 * 16; i += 256)
    reinterpret_cast<float4*>(Wl)[i] = reinterpret_cast<const float4*>(W)[i];
  const int row0 = blockIdx.x * 64;
  for (int i = tid; i < 64 * 32; i += 256) {
    const int r = i >> 5, q = i & 31;
    const int gr = row0 + r;
    const float4 v = (gr < n)
        ? reinterpret_cast<const float4*>(x + (size_t)gr * 128)[q]
        : float4{0.f, 0.f, 0.f, 0.f};
    *reinterpret_cast<float4*>(&xl[r][q * 4]) = v;
  }
  __syncthreads();
  const int r0 = (tid >> 4) << 2;   // rows r0..r0+3
  const int cg = (tid & 15) << 2;   // cols cg..cg+3
  float4 a0{0,0,0,0}, a1{0,0,0,0}, a2{0,0,0,0}, a3{0,0,0,0};
#pragma unroll
  for (int k = 0; k < 128; k += 4) {
    const float4 x0 = *reinterpret_cast<const float4*>(&xl[r0 + 0][k]);
    const float4 x1 = *reinterpret_cast<const float4*>(&xl[r0 + 1][k]);
    const float4 x2 = *reinterpret_cast<const float4*>(&xl[r0 + 2][k]);
    const float4 x3 = *reinterpret_cast<const float4*>(&xl[r0 + 3][k]);
    const float4 w0 = *reinterpret_cast<const float4*>(&Wl[(k + 0) * 64 + cg]);
    const float4 w1 = *reinterpret_cast<const float4*>(&Wl[(k + 1) * 64 + cg]);
    const float4 w2 = *reinterpret_cast<const float4*>(&Wl[(k + 2) * 64 + cg]);
    const float4 w3 = *reinterpret_cast<const float4*>(&Wl[(k + 3) * 64 + cg]);
    FMA4(a0, x0, w0, w1, w2, w3);
    FMA4(a1, x1, w0, w1, w2, w3);
    FMA4(a2, x2, w0, w1, w2, w3);
    FMA4(a3, x3, w0, w1, w2, w3);
  }
  float4 accs[4] = {a0, a1, a2, a3};
#pragma unroll
  for (int i = 0; i < 4; ++i) {
    const int grow = row0 + r0 + i;
    if (grow >= n) break;
    const float di = dinv[grow];
    __half2* op = reinterpret_cast<__half2*>(out + (size_t)grow * 64 + cg);
    op[0] = __floats2half2_rn(accs[i].x * di, accs[i].y * di);
    op[1] = __floats2half2_rn(accs[i].z * di, accs[i].w * di);
  }
}

// ---------------------------------------------------------------- dense transform (fp16 in, K=64)
__global__ __launch_bounds__(256) void gemm_rt64h(const __half* __restrict__ x,
                                                  const float* __restrict__ W,
                                                  const float* __restrict__ dinv,
                                                  __half* __restrict__ out, int n) {
  __shared__ float Wl[64 * 64];    // 16 KB
  __shared__ float xl[64][68];     // 17.4 KB
  const int tid = threadIdx.x;
  for (int i = tid; i < 64 * 16; i += 256)
    reinterpret_cast<float4*>(Wl)[i] = reinterpret_cast<const float4*>(W)[i];
  const int row0 = blockIdx.x * 64;
  for (int i = tid; i < 64 * 8; i += 256) {  // 64 rows x 8 chunks of 8 fp16
    const int r = i >> 3, q = i & 7;
    const int gr = row0 + r;
    if (gr < n) {
      const float4 hv = *reinterpret_cast<const float4*>(
          x + (size_t)gr * 64 + q * 8);
      const __half2* hp = reinterpret_cast<const __half2*>(&hv);
#pragma unroll
      for (int j = 0; j < 4; ++j) {
        const float2 f = __half22float2(hp[j]);
        xl[r][q * 8 + 2 * j + 0] = f.x;
        xl[r][q * 8 + 2 * j + 1] = f.y;
      }
    } else {
#pragma unroll
      for (int j = 0; j < 8; ++j) xl[r][q * 8 + j] = 0.f;
    }
  }
  __syncthreads();
  const int r0 = (tid >> 4) << 2;
  const int cg = (tid & 15) << 2;
  float4 a0{0,0,0,0}, a1{0,0,0,0}, a2{0,0,0,0}, a3{0,0,0,0};
#pragma unroll
  for (int k = 0; k < 64; k += 4) {
    const float4 x0 = *reinterpret_cast<const float4*>(&xl[r0 + 0][k]);
    const float4 x1 = *reinterpret_cast<const float4*>(&xl[r0 + 1][k]);
    const float4 x2 = *reinterpret_cast<const float4*>(&xl[r0 + 2][k]);
    const float4 x3 = *reinterpret_cast<const float4*>(&xl[r0 + 3][k]);
    const float4 w0 = *reinterpret_cast<const float4*>(&Wl[(k + 0) * 64 + cg]);
    const float4 w1 = *reinterpret_cast<const float4*>(&Wl[(k + 1) * 64 + cg]);
    const float4 w2 = *reinterpret_cast<const float4*>(&Wl[(k + 2) * 64 + cg]);
    const float4 w3 = *reinterpret_cast<const float4*>(&Wl[(k + 3) * 64 + cg]);
    FMA4(a0, x0, w0, w1, w2, w3);
    FMA4(a1, x1, w0, w1, w2, w3);
    FMA4(a2, x2, w0, w1, w2, w3);
    FMA4(a3, x3, w0, w1, w2, w3);
  }
  float4 accs[4] = {a0, a1, a2, a3};
#pragma unroll
  for (int i = 0; i < 4; ++i) {
    const int grow = row0 + r0 + i;
    if (grow >= n) break;
    const float di = dinv[grow];
    __half2* op = reinterpret_cast<__half2*>(out + (size_t)grow * 64 + cg);
    op[0] = __floats2half2_rn(accs[i].x * di, accs[i].y * di);
    op[1] = __floats2half2_rn(accs[i].z * di, accs[i].w * di);
  }
}

// ---------------------------------------------------------------- pull aggregation
// one wave per node, 2 edges per load (half2 rows), 16 loads in flight per half
template <bool FP16OUT>
__global__ __launch_bounds__(256) void gather_agg(const int* __restrict__ rowptr,
                                                  const int* __restrict__ colidx,
                                                  const __half2* __restrict__ g2,
                                                  const float* __restrict__ dinv,
                                                  const float* __restrict__ bias,
                                                  void* __restrict__ outp, int n) {
  const int lane = threadIdx.x & 63;
  const int node = (blockIdx.x * 256 + threadIdx.x) >> 6;
  if (node >= n) return;
  const int h = lane >> 5;
  const int l = lane & 31;
  const int beg = rowptr[node];
  const int end = rowptr[node + 1];
  float2 acc = {0.f, 0.f};
  int e = beg + h;
  for (; e + 30 < end; e += 32) {  // 32 edges/wave-iter
    int s[16];
#pragma unroll
    for (int j = 0; j < 16; ++j) s[j] = colidx[e + 2 * j];
    float2 v[16];
#pragma unroll
    for (int j = 0; j < 16; ++j)
      v[j] = __half22float2(g2[((u32)s[j] << 5) + (u32)l]);
#pragma unroll
    for (int j = 0; j < 16; ++j) {
      acc.x += v[j].x;
      acc.y += v[j].y;
    }
  }
  for (; e + 6 < end; e += 8) {
    const int s0 = colidx[e + 0], s1 = colidx[e + 2];
    const int s2 = colidx[e + 4], s3 = colidx[e + 6];
    const float2 v0 = __half22float2(g2[((u32)s0 << 5) + (u32)l]);
    const float2 v1 = __half22float2(g2[((u32)s1 << 5) + (u32)l]);
    const float2 v2 = __half22float2(g2[((u32)s2 << 5) + (u32)l]);
    const float2 v3 = __half22float2(g2[((u32)s3 << 5) + (u32)l]);
    acc.x += (v0.x + v1.x) + (v2.x + v3.x);
    acc.y += (v0.y + v1.y) + (v2.y + v3.y);
  }
  for (; e < end; e += 2) {
    const float2 v = __half22float2(g2[((u32)colidx[e] << 5) + (u32)l]);
    acc.x += v.x;
    acc.y += v.y;
  }
  acc.x += __shfl_xor(acc.x, 32);
  acc.y += __shfl_xor(acc.y, 32);
  const float2 sv = __half22float2(g2[((u32)node << 5) + (u32)l]);  // self-loop
  acc.x += sv.x;
  acc.y += sv.y;
  const float di = dinv[node];
  const float2 bb = reinterpret_cast<const float2*>(bias)[l];
  float2 r;
  r.x = fmaxf(fmaf(acc.x, di, bb.x), 0.f);
  r.y = fmaxf(fmaf(acc.y, di, bb.y), 0.f);
  if (h == 0) {
    if (FP16OUT)
      reinterpret_cast<__half2*>(outp)[(size_t)node * 32 + l] =
          __floats2half2_rn(r.x, r.y);
    else
      reinterpret_cast<float2*>(outp)[(size_t)node * 32 + l] = r;
  }
}

// ---------------------------------------------------------------- final FC (64 -> 11, fp16 in)
__global__ __launch_bounds__(256) void gemm_fc(const __half* __restrict__ h,
                                               const float* __restrict__ W,
                                               const float* __restrict__ b,
                                               float* __restrict__ out) {
  __shared__ float Wl[772];
  __shared__ float xl[16][68];
  const int tid = threadIdx.x;
  for (int i = tid; i < 772; i += 256) Wl[i] = 0.f;
  __syncthreads();
  for (int i = tid; i < 64 * 11; i += 256) Wl[(i / 11) * 12 + (i % 11)] = W[i];
  const int row0 = blockIdx.x * 16;
  if (tid < 128) {  // 16 rows x 8 chunks of 8 fp16
    const int r = tid >> 3, q = tid & 7;
    const float4 hv = *reinterpret_cast<const float4*>(
        h + (size_t)(row0 + r) * 64 + q * 8);
    const __half2* hp = reinterpret_cast<const __half2*>(&hv);
#pragma unroll
    for (int j = 0; j < 4; ++j) {
      const float2 f = __half22float2(hp[j]);
      xl[r][q * 8 + 2 * j + 0] = f.x;
      xl[r][q * 8 + 2 * j + 1] = f.y;
    }
  }
  __syncthreads();
  const int r = tid >> 4, c = tid & 15;
  float acc = 0.f;
#pragma unroll
  for (int k = 0; k < 64; k += 4) {
    acc = fmaf(xl[r][k + 0], Wl[(k + 0) * 12 + c], acc);
    acc = fmaf(xl[r][k + 1], Wl[(k + 1) * 12 + c], acc);
    acc = fmaf(xl[r][k + 2], Wl[(k + 2) * 12 + c], acc);
    acc = fmaf(xl[r][k + 3], Wl[(k + 3) * 12 + c], acc);
  }
  if (c < 11) out[(size_t)(row0 + r) * 11 + c] = acc + b[c];
}

// ---------------------------------------------------------------- launch
extern "C" void kernel_launch(void* const* d_in, const int* in_sizes, int n_in,
                              void* d_out, int out_size, void* d_ws, size_t ws_size,
                              hipStream_t stream) {
  const float* x   = (const float*)d_in[0];
  const int*   ei  = (const int*)d_in[1];   // [2, E] int32
  const float* W1  = (const float*)d_in[2];
  const float* b1  = (const float*)d_in[3];
  const float* W2  = (const float*)d_in[4];
  const float* b2  = (const float*)d_in[5];
  const float* Wfc = (const float*)d_in[6];
  const float* bfc = (const float*)d_in[7];
  float* out = (float*)d_out;

  const int n = in_sizes[0] / 128;  // 100000
  const int E = in_sizes[1] / 2;    // 3200000
  const int* src = ei;
  const int* dst = ei + E;
  const int nbk = (n + BKN - 1) >> SH;  // 196 buckets
  const int NE = nbk * NBLK;            // 100352 count entries

  char* ws = (char*)d_ws;
  size_t o = 0;
  auto alloc = [&](size_t bytes) {
    char* p = ws + o;
    o += (bytes + 255) & ~(size_t)255;
    return p;
  };
  float*  dinv   = (float*) alloc((size_t)n * 4);
  int*    rowptr = (int*)   alloc((size_t)(n + 1) * 4);
  int*    cnt2   = (int*)   alloc((size_t)NE * 4);
  int*    off    = (int*)   alloc((size_t)NE * 4);
  int*    bsum2  = (int*)   alloc(512 * 4);
  int*    boff   = (int*)   alloc((size_t)(nbk + 1) * 4);
  u32*    pairs  = (u32*)   alloc((size_t)E * 4);
  int*    colidx = (int*)   alloc((size_t)E * 4);
  __half* B0h    = (__half*)alloc((size_t)n * HID * 2);  // g fp16
  __half* B1h    = (__half*)alloc((size_t)n * HID * 2);  // h1 / h2 fp16
  if (o > ws_size) return;

  const int nb2 = (NE + 255) / 256;        // offset-scan blocks
  const int gblocks64 = (n + 63) / 64;     // 1563 register-tiled gemm blocks
  const int fcblocks  = n / 16;            // 6250 fc blocks

  // ---- graph preprocessing (deterministic counting sort; no global atomics)
  count_chunks<<<NBLK, 256, 0, stream>>>(dst, cnt2, E, nbk);
  scan_blocks<<<nb2, 256, 0, stream>>>(cnt2, off, bsum2, NE);
  scan_top<<<1, 512, 0, stream>>>(bsum2, nb2);
  add_offsets2<<<nb2, 256, 0, stream>>>(off, bsum2, boff, NE, E, nbk);
  fill_pairs<<<NBLK, 256, 0, stream>>>(src, dst, off, pairs, E, nbk);
  bucket_csr<<<nbk, 512, 0, stream>>>(pairs, boff, rowptr, dinv, colidx, n, nbk);

  const int pull_blocks = (n * 64 + 255) / 256;  // one wave per node

  // ---- layer 1
  gemm_rt128<<<gblocks64, 256, 0, stream>>>(x, W1, dinv, B0h, n);
  gather_agg<true><<<pull_blocks, 256, 0, stream>>>(rowptr, colidx,
      (const __half2*)B0h, dinv, b1, B1h, n);

  // ---- layer 2
  gemm_rt64h<<<gblocks64, 256, 0, stream>>>(B1h, W2, dinv, B0h, n);
  gather_agg<true><<<pull_blocks, 256, 0, stream>>>(rowptr, colidx,
      (const __half2*)B0h, dinv, b2, B1h, n);

  // ---- FC head (fp16 activations in)
  gemm_fc<<<fcblocks, 256, 0, stream>>>(B1h, Wfc, bfc, out);
}

// Round 16
// 276.334 us; speedup vs baseline: 1.2616x; 1.2616x over previous
//
#include <hip/hip_runtime.h>
#include <hip/hip_fp16.h>

#define HID 64
#define SH 9          // log2(nodes per bucket)
#define BKN 512       // nodes per bucket
#define MAXB1 256     // max buckets supported (n <= 131072)
#define NBLK 512      // edge-chunk blocks for the counting sort
#define MAXPAIR 24576 // LDS pair-cache (96 KB); expected bucket size ~16.3K
typedef unsigned int u32;

// ---------------------------------------------------------------- per-(block,bucket) histogram
__global__ __launch_bounds__(256) void count_chunks(const int* __restrict__ dst,
                                                    int* __restrict__ cnt2,
                                                    int E, int nbk) {
  __shared__ int lc[MAXB1];
  const int t = threadIdx.x;
  for (int b = t; b < nbk; b += 256) lc[b] = 0;
  __syncthreads();
  const int C = (E + NBLK - 1) / NBLK;
  const int s0 = blockIdx.x * C;
  const int s1 = min(s0 + C, E);
  for (int i = s0 + t; i < s1; i += 256) atomicAdd(&lc[dst[i] >> SH], 1);
  __syncthreads();
  for (int b = t; b < nbk; b += 256)
    cnt2[(size_t)b * NBLK + blockIdx.x] = lc[b];  // bucket-major for the scan
}

// ---------------------------------------------------------------- hierarchical scan (cnt2)
__global__ __launch_bounds__(256) void scan_blocks(const int* __restrict__ v_in,
                                                   int* __restrict__ excl,
                                                   int* __restrict__ bsum, int n) {
  __shared__ int s[256];
  const int t = threadIdx.x;
  const int i = blockIdx.x * 256 + t;
  const int v = (i < n) ? v_in[i] : 0;
  s[t] = v;
  __syncthreads();
  for (int off = 1; off < 256; off <<= 1) {
    const int u = (t >= off) ? s[t - off] : 0;
    __syncthreads();
    s[t] += u;
    __syncthreads();
  }
  if (i < n) excl[i] = s[t] - v;
  if (t == 255) bsum[blockIdx.x] = s[255];
}

__global__ __launch_bounds__(512) void scan_top(int* bsum, int nb) {
  __shared__ int s[512];
  const int t = threadIdx.x;
  const int v = (t < nb) ? bsum[t] : 0;
  s[t] = v;
  __syncthreads();
  for (int off = 1; off < 512; off <<= 1) {
    const int u = (t >= off) ? s[t - off] : 0;
    __syncthreads();
    s[t] += u;
    __syncthreads();
  }
  if (t < nb) bsum[t] = s[t] - v;
}

__global__ __launch_bounds__(256) void add_offsets2(int* __restrict__ off,
                                                    const int* __restrict__ bsum,
                                                    int* __restrict__ boff,
                                                    int NE, int E, int nbk) {
  const int m = blockIdx.x * 256 + threadIdx.x;
  if (m < NE) {
    const int v = off[m] + bsum[blockIdx.x];
    off[m] = v;
    if ((m & (NBLK - 1)) == 0) boff[m >> 9] = v;  // NBLK = 512
  }
  if (m == 0) boff[nbk] = E;
}

// ---------------------------------------------------------------- fill pairs (deterministic)
// packed u32: (dstLocal<<17) | src
__global__ __launch_bounds__(256) void fill_pairs(const int* __restrict__ src,
                                                  const int* __restrict__ dst,
                                                  const int* __restrict__ off,
                                                  u32* __restrict__ pairs,
                                                  int E, int nbk) {
  __shared__ int lbase[MAXB1];
  __shared__ int lrank[MAXB1];
  const int t = threadIdx.x;
  for (int b = t; b < nbk; b += 256) {
    lbase[b] = off[(size_t)b * NBLK + blockIdx.x];
    lrank[b] = 0;
  }
  __syncthreads();
  const int C = (E + NBLK - 1) / NBLK;
  const int s0 = blockIdx.x * C;
  const int s1 = min(s0 + C, E);
  for (int i = s0 + t; i < s1; i += 256) {
    const int d = dst[i];
    const int b = d >> SH;
    const int r = atomicAdd(&lrank[b], 1);
    pairs[lbase[b] + r] = ((u32)(d & (BKN - 1)) << 17) | (u32)src[i];
  }
}

// ---------------------------------------------------------------- fused CSR build
__global__ __launch_bounds__(512) void bucket_csr(const u32* __restrict__ pairs,
                                                  const int* __restrict__ boff,
                                                  int* __restrict__ rowptr,
                                                  float* __restrict__ dinv,
                                                  int* __restrict__ colidx,
                                                  int n, int nbk) {
  __shared__ u32 pc[MAXPAIR];  // 96 KB pair cache
  __shared__ int ldeg[BKN];
  __shared__ int lofs[BKN];
  const int bkt = blockIdx.x;
  const int t = threadIdx.x;
  ldeg[t] = 0;
  __syncthreads();
  const int beg = boff[bkt], end = boff[bkt + 1];
  const int cnt = end - beg;
  const bool cached = (cnt <= MAXPAIR);
  for (int e = t; e < cnt; e += 512) {
    const u32 p = pairs[beg + e];
    if (cached) pc[e] = p;
    atomicAdd(&ldeg[p >> 17], 1);
  }
  __syncthreads();
  const int v = ldeg[t];
  lofs[t] = v;
  __syncthreads();
  for (int o = 1; o < 512; o <<= 1) {  // Hillis-Steele inclusive scan
    const int u = (t >= o) ? lofs[t - o] : 0;
    __syncthreads();
    lofs[t] += u;
    __syncthreads();
  }
  const int base = beg + lofs[t] - v;  // exclusive
  const int node = bkt * BKN + t;
  if (node < n) {
    rowptr[node] = base;
    dinv[node] = rsqrtf((float)(v + 1));  // +1 self-loop
  }
  if (bkt == nbk - 1 && t == 511) rowptr[n] = end;  // == E
  __syncthreads();
  ldeg[t] = base;  // reuse as absolute cursor
  __syncthreads();
  for (int e = t; e < cnt; e += 512) {
    const u32 p = cached ? pc[e] : pairs[beg + e];
    const int pos = atomicAdd(&ldeg[p >> 17], 1);
    colidx[pos] = (int)(p & 0x1FFFF);
  }
}

// ---------------------------------------------------------------- dense transform (fp32 in)
// g[i, c] = fp16( dinv[i] * sum_k x[i,k] * W[k,c] )
// 16 rows/block, thread = (row, 4-col group): low VGPR, ~41KB LDS, 3 blocks/CU
template <int K>
__global__ __launch_bounds__(256) void gemm_nodes(const float* __restrict__ x,
                                                  const float* __restrict__ W,
                                                  const float* __restrict__ dinv,
                                                  __half* __restrict__ out) {
  __shared__ float Wl[K * 64];
  __shared__ float xl[16][K + 4];
  const int tid = threadIdx.x;
  for (int i = tid; i < K * 16; i += 256)
    reinterpret_cast<float4*>(Wl)[i] = reinterpret_cast<const float4*>(W)[i];
  const int row0 = blockIdx.x * 16;
  for (int i = tid; i < 16 * (K / 4); i += 256) {
    const int r = i / (K / 4), q = i % (K / 4);
    reinterpret_cast<float4*>(&xl[r][0])[q] =
        reinterpret_cast<const float4*>(x + (size_t)(row0 + r) * K)[q];
  }
  __syncthreads();
  const int r = tid >> 4;
  const int cg = (tid & 15) << 2;
  float4 acc = {0.f, 0.f, 0.f, 0.f};
#pragma unroll
  for (int k = 0; k < K; k += 4) {
    const float4 xv = *reinterpret_cast<const float4*>(&xl[r][k]);
    const float4 w0 = *reinterpret_cast<const float4*>(&Wl[(k + 0) * 64 + cg]);
    const float4 w1 = *reinterpret_cast<const float4*>(&Wl[(k + 1) * 64 + cg]);
    const float4 w2 = *reinterpret_cast<const float4*>(&Wl[(k + 2) * 64 + cg]);
    const float4 w3 = *reinterpret_cast<const float4*>(&Wl[(k + 3) * 64 + cg]);
    acc.x = fmaf(xv.w, w3.x, fmaf(xv.z, w2.x, fmaf(xv.y, w1.x, fmaf(xv.x, w0.x, acc.x))));
    acc.y = fmaf(xv.w, w3.y, fmaf(xv.z, w2.y, fmaf(xv.y, w1.y, fmaf(xv.x, w0.y, acc.y))));
    acc.z = fmaf(xv.w, w3.z, fmaf(xv.z, w2.z, fmaf(xv.y, w1.z, fmaf(xv.x, w0.z, acc.z))));
    acc.w = fmaf(xv.w, w3.w, fmaf(xv.z, w2.w, fmaf(xv.y, w1.w, fmaf(xv.x, w0.w, acc.w))));
  }
  const int grow = row0 + r;
  const float di = dinv[grow];
  __half2* op = reinterpret_cast<__half2*>(out + (size_t)grow * 64 + cg);
  op[0] = __floats2half2_rn(acc.x * di, acc.y * di);
  op[1] = __floats2half2_rn(acc.z * di, acc.w * di);
}

// ---------------------------------------------------------------- dense transform (fp16 in, K=64)
__global__ __launch_bounds__(256) void gemm_nodes_h(const __half* __restrict__ x,
                                                    const float* __restrict__ W,
                                                    const float* __restrict__ dinv,
                                                    __half* __restrict__ out) {
  __shared__ float Wl[64 * 64];
  __shared__ float xl[16][68];
  const int tid = threadIdx.x;
  for (int i = tid; i < 64 * 16; i += 256)
    reinterpret_cast<float4*>(Wl)[i] = reinterpret_cast<const float4*>(W)[i];
  const int row0 = blockIdx.x * 16;
  if (tid < 128) {  // 16 rows x 8 chunks of 8 fp16 (16B loads)
    const int r = tid >> 3, q = tid & 7;
    const float4 hv = *reinterpret_cast<const float4*>(
        x + (size_t)(row0 + r) * 64 + q * 8);
    const __half2* hp = reinterpret_cast<const __half2*>(&hv);
#pragma unroll
    for (int j = 0; j < 4; ++j) {
      const float2 f = __half22float2(hp[j]);
      xl[r][q * 8 + 2 * j + 0] = f.x;
      xl[r][q * 8 + 2 * j + 1] = f.y;
    }
  }
  __syncthreads();
  const int r = tid >> 4;
  const int cg = (tid & 15) << 2;
  float4 acc = {0.f, 0.f, 0.f, 0.f};
#pragma unroll
  for (int k = 0; k < 64; k += 4) {
    const float4 xv = *reinterpret_cast<const float4*>(&xl[r][k]);
    const float4 w0 = *reinterpret_cast<const float4*>(&Wl[(k + 0) * 64 + cg]);
    const float4 w1 = *reinterpret_cast<const float4*>(&Wl[(k + 1) * 64 + cg]);
    const float4 w2 = *reinterpret_cast<const float4*>(&Wl[(k + 2) * 64 + cg]);
    const float4 w3 = *reinterpret_cast<const float4*>(&Wl[(k + 3) * 64 + cg]);
    acc.x = fmaf(xv.w, w3.x, fmaf(xv.z, w2.x, fmaf(xv.y, w1.x, fmaf(xv.x, w0.x, acc.x))));
    acc.y = fmaf(xv.w, w3.y, fmaf(xv.z, w2.y, fmaf(xv.y, w1.y, fmaf(xv.x, w0.y, acc.y))));
    acc.z = fmaf(xv.w, w3.z, fmaf(xv.z, w2.z, fmaf(xv.y, w1.z, fmaf(xv.x, w0.z, acc.z))));
    acc.w = fmaf(xv.w, w3.w, fmaf(xv.z, w2.w, fmaf(xv.y, w1.w, fmaf(xv.x, w0.w, acc.w))));
  }
  const int grow = row0 + r;
  const float di = dinv[grow];
  __half2* op = reinterpret_cast<__half2*>(out + (size_t)grow * 64 + cg);
  op[0] = __floats2half2_rn(acc.x * di, acc.y * di);
  op[1] = __floats2half2_rn(acc.z * di, acc.w * di);
}

// ---------------------------------------------------------------- pull aggregation
// one wave per node, 2 edges per load (half2 rows), 16 loads in flight per half
__global__ __launch_bounds__(256) void gather_agg(const int* __restrict__ rowptr,
                                                  const int* __restrict__ colidx,
                                                  const __half2* __restrict__ g2,
                                                  const float* __restrict__ dinv,
                                                  const float* __restrict__ bias,
                                                  __half2* __restrict__ outp, int n) {
  const int lane = threadIdx.x & 63;
  const int node = (blockIdx.x * 256 + threadIdx.x) >> 6;
  if (node >= n) return;
  const int h = lane >> 5;
  const int l = lane & 31;
  const int beg = rowptr[node];
  const int end = rowptr[node + 1];
  float2 acc = {0.f, 0.f};
  int e = beg + h;
  for (; e + 30 < end; e += 32) {  // 32 edges/wave-iter
    int s[16];
#pragma unroll
    for (int j = 0; j < 16; ++j) s[j] = colidx[e + 2 * j];
    float2 v[16];
#pragma unroll
    for (int j = 0; j < 16; ++j)
      v[j] = __half22float2(g2[((u32)s[j] << 5) + (u32)l]);
#pragma unroll
    for (int j = 0; j < 16; ++j) {
      acc.x += v[j].x;
      acc.y += v[j].y;
    }
  }
  for (; e + 6 < end; e += 8) {
    const int s0 = colidx[e + 0], s1 = colidx[e + 2];
    const int s2 = colidx[e + 4], s3 = colidx[e + 6];
    const float2 v0 = __half22float2(g2[((u32)s0 << 5) + (u32)l]);
    const float2 v1 = __half22float2(g2[((u32)s1 << 5) + (u32)l]);
    const float2 v2 = __half22float2(g2[((u32)s2 << 5) + (u32)l]);
    const float2 v3 = __half22float2(g2[((u32)s3 << 5) + (u32)l]);
    acc.x += (v0.x + v1.x) + (v2.x + v3.x);
    acc.y += (v0.y + v1.y) + (v2.y + v3.y);
  }
  for (; e < end; e += 2) {
    const float2 v = __half22float2(g2[((u32)colidx[e] << 5) + (u32)l]);
    acc.x += v.x;
    acc.y += v.y;
  }
  acc.x += __shfl_xor(acc.x, 32);
  acc.y += __shfl_xor(acc.y, 32);
  const float2 sv = __half22float2(g2[((u32)node << 5) + (u32)l]);  // self-loop
  acc.x += sv.x;
  acc.y += sv.y;
  const float di = dinv[node];
  const float2 bb = reinterpret_cast<const float2*>(bias)[l];
  const float rx = fmaxf(fmaf(acc.x, di, bb.x), 0.f);
  const float ry = fmaxf(fmaf(acc.y, di, bb.y), 0.f);
  if (h == 0) outp[(size_t)node * 32 + l] = __floats2half2_rn(rx, ry);
}

// ---------------------------------------------------------------- final FC (64 -> 11, fp16 in)
__global__ __launch_bounds__(256) void gemm_fc(const __half* __restrict__ h,
                                               const float* __restrict__ W,
                                               const float* __restrict__ b,
                                               float* __restrict__ out) {
  __shared__ float Wl[772];
  __shared__ float xl[16][68];
  const int tid = threadIdx.x;
  for (int i = tid; i < 772; i += 256) Wl[i] = 0.f;
  __syncthreads();
  for (int i = tid; i < 64 * 11; i += 256) Wl[(i / 11) * 12 + (i % 11)] = W[i];
  const int row0 = blockIdx.x * 16;
  if (tid < 128) {  // 16 rows x 8 chunks of 8 fp16
    const int r = tid >> 3, q = tid & 7;
    const float4 hv = *reinterpret_cast<const float4*>(
        h + (size_t)(row0 + r) * 64 + q * 8);
    const __half2* hp = reinterpret_cast<const __half2*>(&hv);
#pragma unroll
    for (int j = 0; j < 4; ++j) {
      const float2 f = __half22float2(hp[j]);
      xl[r][q * 8 + 2 * j + 0] = f.x;
      xl[r][q * 8 + 2 * j + 1] = f.y;
    }
  }
  __syncthreads();
  const int r = tid >> 4, c = tid & 15;
  float acc = 0.f;
#pragma unroll
  for (int k = 0; k < 64; k += 4) {
    acc = fmaf(xl[r][k + 0], Wl[(k + 0) * 12 + c], acc);
    acc = fmaf(xl[r][k + 1], Wl[(k + 1) * 12 + c], acc);
    acc = fmaf(xl[r][k + 2], Wl[(k + 2) * 12 + c], acc);
    acc = fmaf(xl[r][k + 3], Wl[(k + 3) * 12 + c], acc);
  }
  if (c < 11) out[(size_t)(row0 + r) * 11 + c] = acc + b[c];
}

// ---------------------------------------------------------------- launch
extern "C" void kernel_launch(void* const* d_in, const int* in_sizes, int n_in,
                              void* d_out, int out_size, void* d_ws, size_t ws_size,
                              hipStream_t stream) {
  const float* x   = (const float*)d_in[0];
  const int*   ei  = (const int*)d_in[1];   // [2, E] int32
  const float* W1  = (const float*)d_in[2];
  const float* b1  = (const float*)d_in[3];
  const float* W2  = (const float*)d_in[4];
  const float* b2  = (const float*)d_in[5];
  const float* Wfc = (const float*)d_in[6];
  const float* bfc = (const float*)d_in[7];
  float* out = (float*)d_out;

  const int n = in_sizes[0] / 128;  // 100000
  const int E = in_sizes[1] / 2;    // 3200000
  const int* src = ei;
  const int* dst = ei + E;
  const int nbk = (n + BKN - 1) >> SH;  // 196 buckets
  const int NE = nbk * NBLK;            // 100352 count entries

  char* ws = (char*)d_ws;
  size_t o = 0;
  auto alloc = [&](size_t bytes) {
    char* p = ws + o;
    o += (bytes + 255) & ~(size_t)255;
    return p;
  };
  float*  dinv   = (float*) alloc((size_t)n * 4);
  int*    rowptr = (int*)   alloc((size_t)(n + 1) * 4);
  int*    cnt2   = (int*)   alloc((size_t)NE * 4);
  int*    off    = (int*)   alloc((size_t)NE * 4);
  int*    bsum2  = (int*)   alloc(512 * 4);
  int*    boff   = (int*)   alloc((size_t)(nbk + 1) * 4);
  u32*    pairs  = (u32*)   alloc((size_t)E * 4);
  int*    colidx = (int*)   alloc((size_t)E * 4);
  __half* B0h    = (__half*)alloc((size_t)n * HID * 2);  // g fp16
  __half* B1h    = (__half*)alloc((size_t)n * HID * 2);  // h1 / h2 fp16
  if (o > ws_size) return;

  const int nb2 = (NE + 255) / 256;  // offset-scan blocks
  const int gblocks = n / 16;        // 6250 gemm blocks

  // ---- graph preprocessing (deterministic counting sort; no global atomics)
  count_chunks<<<NBLK, 256, 0, stream>>>(dst, cnt2, E, nbk);
  scan_blocks<<<nb2, 256, 0, stream>>>(cnt2, off, bsum2, NE);
  scan_top<<<1, 512, 0, stream>>>(bsum2, nb2);
  add_offsets2<<<nb2, 256, 0, stream>>>(off, bsum2, boff, NE, E, nbk);
  fill_pairs<<<NBLK, 256, 0, stream>>>(src, dst, off, pairs, E, nbk);
  bucket_csr<<<nbk, 512, 0, stream>>>(pairs, boff, rowptr, dinv, colidx, n, nbk);

  const int pull_blocks = (n * 64 + 255) / 256;  // one wave per node

  // ---- layer 1
  gemm_nodes<128><<<gblocks, 256, 0, stream>>>(x, W1, dinv, B0h);
  gather_agg<<<pull_blocks, 256, 0, stream>>>(rowptr, colidx,
      (const __half2*)B0h, dinv, b1, (__half2*)B1h, n);

  // ---- layer 2
  gemm_nodes_h<<<gblocks, 256, 0, stream>>>(B1h, W2, dinv, B0h);
  gather_agg<<<pull_blocks, 256, 0, stream>>>(rowptr, colidx,
      (const __half2*)B0h, dinv, b2, (__half2*)B1h, n);

  // ---- FC head (fp16 activations in)
  gemm_fc<<<gblocks, 256, 0, stream>>>(B1h, Wfc, bfc, out);
}

// Round 17
// 271.293 us; speedup vs baseline: 1.2851x; 1.0186x over previous
//
#include <hip/hip_runtime.h>
#include <hip/hip_fp16.h>

#define HID 64
#define SH 9          // log2(nodes per bucket)
#define BKN 512       // nodes per bucket
#define MAXB1 256     // max buckets supported (n <= 131072)
#define NBLK 512      // edge-chunk blocks for the counting sort
typedef unsigned int u32;

// ---------------------------------------------------------------- per-(block,bucket) histogram
__global__ __launch_bounds__(256) void count_chunks(const int* __restrict__ dst,
                                                    int* __restrict__ cnt2,
                                                    int E, int nbk) {
  __shared__ int lc[MAXB1];
  const int t = threadIdx.x;
  for (int b = t; b < nbk; b += 256) lc[b] = 0;
  __syncthreads();
  const int C = (E + NBLK - 1) / NBLK;
  const int s0 = blockIdx.x * C;
  const int s1 = min(s0 + C, E);
  for (int i = s0 + t; i < s1; i += 256) atomicAdd(&lc[dst[i] >> SH], 1);
  __syncthreads();
  for (int b = t; b < nbk; b += 256)
    cnt2[(size_t)b * NBLK + blockIdx.x] = lc[b];  // bucket-major for the scan
}

// ---------------------------------------------------------------- hierarchical scan (cnt2)
__global__ __launch_bounds__(256) void scan_blocks(const int* __restrict__ v_in,
                                                   int* __restrict__ excl,
                                                   int* __restrict__ bsum, int n) {
  __shared__ int s[256];
  const int t = threadIdx.x;
  const int i = blockIdx.x * 256 + t;
  const int v = (i < n) ? v_in[i] : 0;
  s[t] = v;
  __syncthreads();
  for (int off = 1; off < 256; off <<= 1) {
    const int u = (t >= off) ? s[t - off] : 0;
    __syncthreads();
    s[t] += u;
    __syncthreads();
  }
  if (i < n) excl[i] = s[t] - v;
  if (t == 255) bsum[blockIdx.x] = s[255];
}

__global__ __launch_bounds__(512) void scan_top(int* bsum, int nb) {
  __shared__ int s[512];
  const int t = threadIdx.x;
  const int v = (t < nb) ? bsum[t] : 0;
  s[t] = v;
  __syncthreads();
  for (int off = 1; off < 512; off <<= 1) {
    const int u = (t >= off) ? s[t - off] : 0;
    __syncthreads();
    s[t] += u;
    __syncthreads();
  }
  if (t < nb) bsum[t] = s[t] - v;
}

__global__ __launch_bounds__(256) void add_offsets2(int* __restrict__ off,
                                                    const int* __restrict__ bsum,
                                                    int* __restrict__ boff,
                                                    int NE, int E, int nbk) {
  const int m = blockIdx.x * 256 + threadIdx.x;
  if (m < NE) {
    const int v = off[m] + bsum[blockIdx.x];
    off[m] = v;
    if ((m & (NBLK - 1)) == 0) boff[m >> 9] = v;  // NBLK = 512
  }
  if (m == 0) boff[nbk] = E;
}

// ---------------------------------------------------------------- fill pairs (deterministic)
// packed u32: (dstLocal<<17) | src.  512 threads: 2x TLP for the scatter.
__global__ __launch_bounds__(512) void fill_pairs(const int* __restrict__ src,
                                                  const int* __restrict__ dst,
                                                  const int* __restrict__ off,
                                                  u32* __restrict__ pairs,
                                                  int E, int nbk) {
  __shared__ int lbase[MAXB1];
  __shared__ int lrank[MAXB1];
  const int t = threadIdx.x;
  for (int b = t; b < nbk; b += 512) {
    lbase[b] = off[(size_t)b * NBLK + blockIdx.x];
    lrank[b] = 0;
  }
  __syncthreads();
  const int C = (E + NBLK - 1) / NBLK;
  const int s0 = blockIdx.x * C;
  const int s1 = min(s0 + C, E);
  for (int i = s0 + t; i < s1; i += 512) {
    const int d = dst[i];
    const int b = d >> SH;
    const int r = atomicAdd(&lrank[b], 1);
    pairs[lbase[b] + r] = ((u32)(d & (BKN - 1)) << 17) | (u32)src[i];
  }
}

// ---------------------------------------------------------------- fused CSR build
// 1024 threads/block, no LDS pair cache (phase-2 re-read is L2-hot): 4x TLP
__global__ __launch_bounds__(1024) void bucket_csr(const u32* __restrict__ pairs,
                                                   const int* __restrict__ boff,
                                                   int* __restrict__ rowptr,
                                                   float* __restrict__ dinv,
                                                   int* __restrict__ colidx,
                                                   int n, int nbk) {
  __shared__ int ldeg[BKN];
  __shared__ int lofs[BKN];
  const int bkt = blockIdx.x;
  const int t = threadIdx.x;
  if (t < BKN) ldeg[t] = 0;
  __syncthreads();
  const int beg = boff[bkt], end = boff[bkt + 1];
  const int cnt = end - beg;
  for (int e = t; e < cnt; e += 1024)
    atomicAdd(&ldeg[pairs[beg + e] >> 17], 1);
  __syncthreads();
  if (t < BKN) lofs[t] = ldeg[t];
  __syncthreads();
  for (int o = 1; o < BKN; o <<= 1) {  // Hillis-Steele inclusive scan (512 wide)
    int u = 0;
    if (t < BKN && t >= o) u = lofs[t - o];
    __syncthreads();
    if (t < BKN) lofs[t] += u;
    __syncthreads();
  }
  if (t < BKN) {
    const int v = ldeg[t];
    const int base = beg + lofs[t] - v;  // exclusive
    const int node = bkt * BKN + t;
    if (node < n) {
      rowptr[node] = base;
      dinv[node] = rsqrtf((float)(v + 1));  // +1 self-loop
    }
    ldeg[t] = base;  // reuse as absolute cursor
  }
  if (bkt == nbk - 1 && t == 0) rowptr[n] = end;  // == E
  __syncthreads();
  for (int e = t; e < cnt; e += 1024) {
    const u32 p = pairs[beg + e];  // L2-hot re-read (65KB window)
    const int pos = atomicAdd(&ldeg[p >> 17], 1);
    colidx[pos] = (int)(p & 0x1FFFF);
  }
}

// ---------------------------------------------------------------- dense transform (fp32 in)
// g[i, c] = fp16( dinv[i] * sum_k x[i,k] * W[k,c] )
// 16 rows/block, thread = (row, 4-col group): low VGPR, ~41KB LDS, 3 blocks/CU
template <int K>
__global__ __launch_bounds__(256) void gemm_nodes(const float* __restrict__ x,
                                                  const float* __restrict__ W,
                                                  const float* __restrict__ dinv,
                                                  __half* __restrict__ out) {
  __shared__ float Wl[K * 64];
  __shared__ float xl[16][K + 4];
  const int tid = threadIdx.x;
  for (int i = tid; i < K * 16; i += 256)
    reinterpret_cast<float4*>(Wl)[i] = reinterpret_cast<const float4*>(W)[i];
  const int row0 = blockIdx.x * 16;
  for (int i = tid; i < 16 * (K / 4); i += 256) {
    const int r = i / (K / 4), q = i % (K / 4);
    reinterpret_cast<float4*>(&xl[r][0])[q] =
        reinterpret_cast<const float4*>(x + (size_t)(row0 + r) * K)[q];
  }
  __syncthreads();
  const int r = tid >> 4;
  const int cg = (tid & 15) << 2;
  float4 acc = {0.f, 0.f, 0.f, 0.f};
#pragma unroll
  for (int k = 0; k < K; k += 4) {
    const float4 xv = *reinterpret_cast<const float4*>(&xl[r][k]);
    const float4 w0 = *reinterpret_cast<const float4*>(&Wl[(k + 0) * 64 + cg]);
    const float4 w1 = *reinterpret_cast<const float4*>(&Wl[(k + 1) * 64 + cg]);
    const float4 w2 = *reinterpret_cast<const float4*>(&Wl[(k + 2) * 64 + cg]);
    const float4 w3 = *reinterpret_cast<const float4*>(&Wl[(k + 3) * 64 + cg]);
    acc.x = fmaf(xv.w, w3.x, fmaf(xv.z, w2.x, fmaf(xv.y, w1.x, fmaf(xv.x, w0.x, acc.x))));
    acc.y = fmaf(xv.w, w3.y, fmaf(xv.z, w2.y, fmaf(xv.y, w1.y, fmaf(xv.x, w0.y, acc.y))));
    acc.z = fmaf(xv.w, w3.z, fmaf(xv.z, w2.z, fmaf(xv.y, w1.z, fmaf(xv.x, w0.z, acc.z))));
    acc.w = fmaf(xv.w, w3.w, fmaf(xv.z, w2.w, fmaf(xv.y, w1.w, fmaf(xv.x, w0.w, acc.w))));
  }
  const int grow = row0 + r;
  const float di = dinv[grow];
  __half2* op = reinterpret_cast<__half2*>(out + (size_t)grow * 64 + cg);
  op[0] = __floats2half2_rn(acc.x * di, acc.y * di);
  op[1] = __floats2half2_rn(acc.z * di, acc.w * di);
}

// ---------------------------------------------------------------- dense transform (fp16 in, K=64)
__global__ __launch_bounds__(256) void gemm_nodes_h(const __half* __restrict__ x,
                                                    const float* __restrict__ W,
                                                    const float* __restrict__ dinv,
                                                    __half* __restrict__ out) {
  __shared__ float Wl[64 * 64];
  __shared__ float xl[16][68];
  const int tid = threadIdx.x;
  for (int i = tid; i < 64 * 16; i += 256)
    reinterpret_cast<float4*>(Wl)[i] = reinterpret_cast<const float4*>(W)[i];
  const int row0 = blockIdx.x * 16;
  if (tid < 128) {  // 16 rows x 8 chunks of 8 fp16 (16B loads)
    const int r = tid >> 3, q = tid & 7;
    const float4 hv = *reinterpret_cast<const float4*>(
        x + (size_t)(row0 + r) * 64 + q * 8);
    const __half2* hp = reinterpret_cast<const __half2*>(&hv);
#pragma unroll
    for (int j = 0; j < 4; ++j) {
      const float2 f = __half22float2(hp[j]);
      xl[r][q * 8 + 2 * j + 0] = f.x;
      xl[r][q * 8 + 2 * j + 1] = f.y;
    }
  }
  __syncthreads();
  const int r = tid >> 4;
  const int cg = (tid & 15) << 2;
  float4 acc = {0.f, 0.f, 0.f, 0.f};
#pragma unroll
  for (int k = 0; k < 64; k += 4) {
    const float4 xv = *reinterpret_cast<const float4*>(&xl[r][k]);
    const float4 w0 = *reinterpret_cast<const float4*>(&Wl[(k + 0) * 64 + cg]);
    const float4 w1 = *reinterpret_cast<const float4*>(&Wl[(k + 1) * 64 + cg]);
    const float4 w2 = *reinterpret_cast<const float4*>(&Wl[(k + 2) * 64 + cg]);
    const float4 w3 = *reinterpret_cast<const float4*>(&Wl[(k + 3) * 64 + cg]);
    acc.x = fmaf(xv.w, w3.x, fmaf(xv.z, w2.x, fmaf(xv.y, w1.x, fmaf(xv.x, w0.x, acc.x))));
    acc.y = fmaf(xv.w, w3.y, fmaf(xv.z, w2.y, fmaf(xv.y, w1.y, fmaf(xv.x, w0.y, acc.y))));
    acc.z = fmaf(xv.w, w3.z, fmaf(xv.z, w2.z, fmaf(xv.y, w1.z, fmaf(xv.x, w0.z, acc.z))));
    acc.w = fmaf(xv.w, w3.w, fmaf(xv.z, w2.w, fmaf(xv.y, w1.w, fmaf(xv.x, w0.w, acc.w))));
  }
  const int grow = row0 + r;
  const float di = dinv[grow];
  __half2* op = reinterpret_cast<__half2*>(out + (size_t)grow * 64 + cg);
  op[0] = __floats2half2_rn(acc.x * di, acc.y * di);
  op[1] = __floats2half2_rn(acc.z * di, acc.w * di);
}

// ---------------------------------------------------------------- pull aggregation
// one wave per node, 2 edges per load (half2 rows), 16 loads in flight per half
__global__ __launch_bounds__(256) void gather_agg(const int* __restrict__ rowptr,
                                                  const int* __restrict__ colidx,
                                                  const __half2* __restrict__ g2,
                                                  const float* __restrict__ dinv,
                                                  const float* __restrict__ bias,
                                                  __half2* __restrict__ outp, int n) {
  const int lane = threadIdx.x & 63;
  const int node = (blockIdx.x * 256 + threadIdx.x) >> 6;
  if (node >= n) return;
  const int h = lane >> 5;
  const int l = lane & 31;
  const int beg = rowptr[node];
  const int end = rowptr[node + 1];
  float2 acc = {0.f, 0.f};
  int e = beg + h;
  for (; e + 30 < end; e += 32) {  // 32 edges/wave-iter
    int s[16];
#pragma unroll
    for (int j = 0; j < 16; ++j) s[j] = colidx[e + 2 * j];
    float2 v[16];
#pragma unroll
    for (int j = 0; j < 16; ++j)
      v[j] = __half22float2(g2[((u32)s[j] << 5) + (u32)l]);
#pragma unroll
    for (int j = 0; j < 16; ++j) {
      acc.x += v[j].x;
      acc.y += v[j].y;
    }
  }
  for (; e + 6 < end; e += 8) {
    const int s0 = colidx[e + 0], s1 = colidx[e + 2];
    const int s2 = colidx[e + 4], s3 = colidx[e + 6];
    const float2 v0 = __half22float2(g2[((u32)s0 << 5) + (u32)l]);
    const float2 v1 = __half22float2(g2[((u32)s1 << 5) + (u32)l]);
    const float2 v2 = __half22float2(g2[((u32)s2 << 5) + (u32)l]);
    const float2 v3 = __half22float2(g2[((u32)s3 << 5) + (u32)l]);
    acc.x += (v0.x + v1.x) + (v2.x + v3.x);
    acc.y += (v0.y + v1.y) + (v2.y + v3.y);
  }
  for (; e < end; e += 2) {
    const float2 v = __half22float2(g2[((u32)colidx[e] << 5) + (u32)l]);
    acc.x += v.x;
    acc.y += v.y;
  }
  acc.x += __shfl_xor(acc.x, 32);
  acc.y += __shfl_xor(acc.y, 32);
  const float2 sv = __half22float2(g2[((u32)node << 5) + (u32)l]);  // self-loop
  acc.x += sv.x;
  acc.y += sv.y;
  const float di = dinv[node];
  const float2 bb = reinterpret_cast<const float2*>(bias)[l];
  const float rx = fmaxf(fmaf(acc.x, di, bb.x), 0.f);
  const float ry = fmaxf(fmaf(acc.y, di, bb.y), 0.f);
  if (h == 0) outp[(size_t)node * 32 + l] = __floats2half2_rn(rx, ry);
}

// ---------------------------------------------------------------- final FC (64 -> 11, fp16 in)
// 64 rows/block: W-stage amortized over 4 row-groups
__global__ __launch_bounds__(256) void gemm_fc(const __half* __restrict__ h,
                                               const float* __restrict__ W,
                                               const float* __restrict__ b,
                                               float* __restrict__ out, int n) {
  __shared__ float Wl[772];
  __shared__ float xl[16][68];
  const int tid = threadIdx.x;
  for (int i = tid; i < 772; i += 256) Wl[i] = 0.f;
  __syncthreads();
  for (int i = tid; i < 64 * 11; i += 256) Wl[(i / 11) * 12 + (i % 11)] = W[i];
  const int row00 = blockIdx.x * 64;
  for (int rr = 0; rr < 4; ++rr) {
    const int row0 = row00 + rr * 16;
    __syncthreads();  // covers Wl fill (rr=0) and xl reuse (rr>0)
    if (tid < 128) {  // 16 rows x 8 chunks of 8 fp16
      const int r = tid >> 3, q = tid & 7;
      const int grow = row0 + r;
      if (grow < n) {
        const float4 hv = *reinterpret_cast<const float4*>(
            h + (size_t)grow * 64 + q * 8);
        const __half2* hp = reinterpret_cast<const __half2*>(&hv);
#pragma unroll
        for (int j = 0; j < 4; ++j) {
          const float2 f = __half22float2(hp[j]);
          xl[r][q * 8 + 2 * j + 0] = f.x;
          xl[r][q * 8 + 2 * j + 1] = f.y;
        }
      }
    }
    __syncthreads();
    const int r = tid >> 4, c = tid & 15;
    float acc = 0.f;
#pragma unroll
    for (int k = 0; k < 64; k += 4) {
      acc = fmaf(xl[r][k + 0], Wl[(k + 0) * 12 + c], acc);
      acc = fmaf(xl[r][k + 1], Wl[(k + 1) * 12 + c], acc);
      acc = fmaf(xl[r][k + 2], Wl[(k + 2) * 12 + c], acc);
      acc = fmaf(xl[r][k + 3], Wl[(k + 3) * 12 + c], acc);
    }
    const int grow = row0 + r;
    if (c < 11 && grow < n) out[(size_t)grow * 11 + c] = acc + b[c];
  }
}

// ---------------------------------------------------------------- launch
extern "C" void kernel_launch(void* const* d_in, const int* in_sizes, int n_in,
                              void* d_out, int out_size, void* d_ws, size_t ws_size,
                              hipStream_t stream) {
  const float* x   = (const float*)d_in[0];
  const int*   ei  = (const int*)d_in[1];   // [2, E] int32
  const float* W1  = (const float*)d_in[2];
  const float* b1  = (const float*)d_in[3];
  const float* W2  = (const float*)d_in[4];
  const float* b2  = (const float*)d_in[5];
  const float* Wfc = (const float*)d_in[6];
  const float* bfc = (const float*)d_in[7];
  float* out = (float*)d_out;

  const int n = in_sizes[0] / 128;  // 100000
  const int E = in_sizes[1] / 2;    // 3200000
  const int* src = ei;
  const int* dst = ei + E;
  const int nbk = (n + BKN - 1) >> SH;  // 196 buckets
  const int NE = nbk * NBLK;            // 100352 count entries

  char* ws = (char*)d_ws;
  size_t o = 0;
  auto alloc = [&](size_t bytes) {
    char* p = ws + o;
    o += (bytes + 255) & ~(size_t)255;
    return p;
  };
  float*  dinv   = (float*) alloc((size_t)n * 4);
  int*    rowptr = (int*)   alloc((size_t)(n + 1) * 4);
  int*    cnt2   = (int*)   alloc((size_t)NE * 4);
  int*    off    = (int*)   alloc((size_t)NE * 4);
  int*    bsum2  = (int*)   alloc(512 * 4);
  int*    boff   = (int*)   alloc((size_t)(nbk + 1) * 4);
  u32*    pairs  = (u32*)   alloc((size_t)E * 4);
  int*    colidx = (int*)   alloc((size_t)E * 4);
  __half* B0h    = (__half*)alloc((size_t)n * HID * 2);  // g fp16
  __half* B1h    = (__half*)alloc((size_t)n * HID * 2);  // h1 / h2 fp16
  if (o > ws_size) return;

  const int nb2 = (NE + 255) / 256;  // offset-scan blocks
  const int gblocks = n / 16;        // 6250 gemm blocks
  const int fcblocks = (n + 63) / 64;

  // ---- graph preprocessing (deterministic counting sort; no global atomics)
  count_chunks<<<NBLK, 256, 0, stream>>>(dst, cnt2, E, nbk);
  scan_blocks<<<nb2, 256, 0, stream>>>(cnt2, off, bsum2, NE);
  scan_top<<<1, 512, 0, stream>>>(bsum2, nb2);
  add_offsets2<<<nb2, 256, 0, stream>>>(off, bsum2, boff, NE, E, nbk);
  fill_pairs<<<NBLK, 512, 0, stream>>>(src, dst, off, pairs, E, nbk);
  bucket_csr<<<nbk, 1024, 0, stream>>>(pairs, boff, rowptr, dinv, colidx, n, nbk);

  const int pull_blocks = (n * 64 + 255) / 256;  // one wave per node

  // ---- layer 1
  gemm_nodes<128><<<gblocks, 256, 0, stream>>>(x, W1, dinv, B0h);
  gather_agg<<<pull_blocks, 256, 0, stream>>>(rowptr, colidx,
      (const __half2*)B0h, dinv, b1, (__half2*)B1h, n);

  // ---- layer 2
  gemm_nodes_h<<<gblocks, 256, 0, stream>>>(B1h, W2, dinv, B0h);
  gather_agg<<<pull_blocks, 256, 0, stream>>>(rowptr, colidx,
      (const __half2*)B0h, dinv, b2, (__half2*)B1h, n);

  // ---- FC head (fp16 activations in, 64 rows/block)
  gemm_fc<<<fcblocks, 256, 0, stream>>>(B1h, Wfc, bfc, out, n);
}